// Round 1
// baseline (2189.190 us; speedup 1.0000x reference)
//
#include <hip/hip_runtime.h>
#include <math.h>

#define LE 1024
#define LS 1024
#define DE 1024
#define DS 1024
#define BATCH 16

// ---------------------------------------------------------------------------
// Generic 128x128x16 fp32 tiled GEMM, 256 threads, 8x8 per-thread microtile.
// TA==0: A is row-major M x K  (a[m*lda + k])
// TA==1: A is K x M            (a[k*lda + m])   [i.e. A^T given row-major]
// TB==0: B is N x K            (b[n*ldb + k])   [i.e. C = A * B^T]
// TB==1: B is K x N            (b[k*ldb + n])
// K is hard-coded to 1024 (true for all four GEMMs in this problem).
// All of M, N are multiples of 128 -> no bounds checks.
// Register mapping is interleaved (stride 16) so LDS reads are conflict-free.
// ---------------------------------------------------------------------------
template <int TA, int TB>
__global__ __launch_bounds__(256) void gemm_kernel(
    const float* __restrict__ A, const float* __restrict__ B,
    float* __restrict__ C, int lda, int ldb, int ldc,
    long long sA, long long sB, long long sC) {
  constexpr int BM = 128, BN = 128, BK = 16;
  __shared__ float As[BK][BM + 4];
  __shared__ float Bs[BK][BN + 4];

  const int z = blockIdx.z;
  A += (long long)z * sA;
  B += (long long)z * sB;
  C += (long long)z * sC;

  const int tid = threadIdx.x;
  const int bm = blockIdx.x * BM;
  const int bn = blockIdx.y * BN;
  const int tx = tid & 15;   // N direction
  const int ty = tid >> 4;   // M direction

  float acc[8][8];
#pragma unroll
  for (int i = 0; i < 8; i++)
#pragma unroll
    for (int j = 0; j < 8; j++) acc[i][j] = 0.f;

  for (int k0 = 0; k0 < 1024; k0 += BK) {
    if (TA == 0) {
      const int row = tid >> 1;
      const int colg = (tid & 1) << 3;
      const float* p = A + (long long)(bm + row) * lda + k0 + colg;
      float4 v0 = *(const float4*)p;
      float4 v1 = *(const float4*)(p + 4);
      As[colg + 0][row] = v0.x; As[colg + 1][row] = v0.y;
      As[colg + 2][row] = v0.z; As[colg + 3][row] = v0.w;
      As[colg + 4][row] = v1.x; As[colg + 5][row] = v1.y;
      As[colg + 6][row] = v1.z; As[colg + 7][row] = v1.w;
    } else {
      const int kk = tid >> 4;
      const int mm = (tid & 15) << 3;
      const float* p = A + (long long)(k0 + kk) * lda + bm + mm;
      float4 v0 = *(const float4*)p;
      float4 v1 = *(const float4*)(p + 4);
      *(float4*)&As[kk][mm] = v0;
      *(float4*)&As[kk][mm + 4] = v1;
    }
    if (TB == 0) {
      const int row = tid >> 1;
      const int colg = (tid & 1) << 3;
      const float* p = B + (long long)(bn + row) * ldb + k0 + colg;
      float4 v0 = *(const float4*)p;
      float4 v1 = *(const float4*)(p + 4);
      Bs[colg + 0][row] = v0.x; Bs[colg + 1][row] = v0.y;
      Bs[colg + 2][row] = v0.z; Bs[colg + 3][row] = v0.w;
      Bs[colg + 4][row] = v1.x; Bs[colg + 5][row] = v1.y;
      Bs[colg + 6][row] = v1.z; Bs[colg + 7][row] = v1.w;
    } else {
      const int kk = tid >> 4;
      const int nn = (tid & 15) << 3;
      const float* p = B + (long long)(k0 + kk) * ldb + bn + nn;
      float4 v0 = *(const float4*)p;
      float4 v1 = *(const float4*)(p + 4);
      *(float4*)&Bs[kk][nn] = v0;
      *(float4*)&Bs[kk][nn + 4] = v1;
    }
    __syncthreads();
#pragma unroll
    for (int k = 0; k < BK; k++) {
      float a[8], bb[8];
#pragma unroll
      for (int i = 0; i < 8; i++) a[i] = As[k][ty + (i << 4)];
#pragma unroll
      for (int j = 0; j < 8; j++) bb[j] = Bs[k][tx + (j << 4)];
#pragma unroll
      for (int i = 0; i < 8; i++)
#pragma unroll
        for (int j = 0; j < 8; j++) acc[i][j] = fmaf(a[i], bb[j], acc[i][j]);
    }
    __syncthreads();
  }

#pragma unroll
  for (int i = 0; i < 8; i++) {
    float* cp = C + (long long)(bm + ty + (i << 4)) * ldc + bn + tx;
#pragma unroll
    for (int j = 0; j < 8; j++) cp[j << 4] = acc[i][j];
  }
}

// ---------------------------------------------------------------------------
// Wave (64-lane) reductions
// ---------------------------------------------------------------------------
__device__ inline float waveMax(float v) {
#pragma unroll
  for (int o = 32; o > 0; o >>= 1) v = fmaxf(v, __shfl_down(v, o, 64));
  return v;
}
__device__ inline float waveSum(float v) {
#pragma unroll
  for (int o = 32; o > 0; o >>= 1) v += __shfl_down(v, o, 64);
  return v;
}

// ---------------------------------------------------------------------------
// edit_weights: softmax over src positions (last axis), masked where
// src_sent_masks[b,l] != 0 (those weights become 0). One block per (b,e) row.
// ---------------------------------------------------------------------------
__global__ __launch_bounds__(256) void row_softmax_kernel(
    const float* __restrict__ sim, const int* __restrict__ smask,
    float* __restrict__ out) {
  const int row = blockIdx.x;  // b*LE + e
  const int b = row >> 10;
  const float* x = sim + ((size_t)row << 10);
  const int* mk = smask + (b << 10);
  const int t = threadIdx.x;

  float4 v = ((const float4*)x)[t];
  int4 m = ((const int4*)mk)[t];
  float vv[4] = {v.x, v.y, v.z, v.w};
  const int mmv[4] = {m.x, m.y, m.z, m.w};

  float mx = -3.0e38f;
#pragma unroll
  for (int i = 0; i < 4; i++)
    if (!mmv[i]) mx = fmaxf(mx, vv[i]);

  __shared__ float red[4];
  float wm = waveMax(mx);
  const int wave = t >> 6;
  if ((t & 63) == 0) red[wave] = wm;
  __syncthreads();
  mx = fmaxf(fmaxf(red[0], red[1]), fmaxf(red[2], red[3]));
  __syncthreads();

  float s = 0.f;
#pragma unroll
  for (int i = 0; i < 4; i++) {
    float e = mmv[i] ? 0.f : __expf(vv[i] - mx);
    vv[i] = e;
    s += e;
  }
  float ws = waveSum(s);
  if ((t & 63) == 0) red[wave] = ws;
  __syncthreads();
  s = red[0] + red[1] + red[2] + red[3];
  float inv = 1.0f / s;

  float4 o = make_float4(vv[0] * inv, vv[1] * inv, vv[2] * inv, vv[3] * inv);
  ((float4*)(out + ((size_t)row << 10)))[t] = o;
}

// ---------------------------------------------------------------------------
// src_weights: softmax over edit positions (axis 1), masked where
// edit_sent_masks[b,e] != 0. In-place on sim. Block = 64 columns x 4 e-groups.
// ---------------------------------------------------------------------------
__global__ __launch_bounds__(256) void col_softmax_kernel(
    float* __restrict__ sim, const int* __restrict__ emask) {
  const int b = blockIdx.y;
  const int lane = threadIdx.x & 63;
  const int grp = threadIdx.x >> 6;
  const int l = (blockIdx.x << 6) + lane;
  float* base = sim + ((size_t)b << 20) + l;
  const int* mk = emask + (b << 10);

  float mx = -3.0e38f, sum = 0.f;
  for (int e = grp; e < 1024; e += 4) {
    if (mk[e]) continue;
    float v = base[(size_t)e << 10];
    float nm = fmaxf(mx, v);
    sum = sum * __expf(mx - nm) + __expf(v - nm);
    mx = nm;
  }

  __shared__ float smx[4][64], ssum[4][64];
  smx[grp][lane] = mx;
  ssum[grp][lane] = sum;
  __syncthreads();
  float M = fmaxf(fmaxf(smx[0][lane], smx[1][lane]),
                  fmaxf(smx[2][lane], smx[3][lane]));
  float S = 0.f;
#pragma unroll
  for (int g = 0; g < 4; g++) S += ssum[g][lane] * __expf(smx[g][lane] - M);
  float inv = 1.0f / S;

  for (int e = grp; e < 1024; e += 4) {
    size_t off = (size_t)e << 10;
    float w = mk[e] ? 0.f : __expf(base[off] - M) * inv;
    base[off] = w;
  }
}

// ---------------------------------------------------------------------------
// Launch: proj -> sim -> row softmax (edit_weights reuses proj buffer) ->
// col softmax (in-place) -> edit_ctx -> src_ctx.
// Workspace: proj 64MB + sim 64MB = 128MB.
// ---------------------------------------------------------------------------
extern "C" void kernel_launch(void* const* d_in, const int* in_sizes, int n_in,
                              void* d_out, int out_size, void* d_ws,
                              size_t ws_size, hipStream_t stream) {
  const float* edit = (const float*)d_in[0];   // (B, LE, DE)
  const float* src = (const float*)d_in[1];    // (B, LS, DS)
  const int* emask = (const int*)d_in[2];      // (B, LE)
  const int* smask = (const int*)d_in[3];      // (B, LS)
  const float* W = (const float*)d_in[4];      // (DS, DE)

  float* out_edit = (float*)d_out;                              // (B, LE, DS)
  float* out_src = (float*)d_out + (size_t)BATCH * LE * DS;     // (B, LS, DE)

  float* proj = (float*)d_ws;                        // (B, LE, DS) 64MB
  float* sim = proj + (size_t)BATCH * LE * DS;       // (B, LE, LS) 64MB

  dim3 blk(256);
  const long long S1 = 1LL << 20;  // 1024*1024 per-batch stride

  // 1. proj = edit @ W^T   (M=B*LE=16384, N=DS, K=DE); A row-major, B is N x K
  gemm_kernel<0, 0><<<dim3(128, 8, 1), blk, 0, stream>>>(
      edit, W, proj, DE, DE, DS, 0, 0, 0);

  // 2. sim[b] = proj[b] @ src[b]^T  (M=LE, N=LS, K=DS)
  gemm_kernel<0, 0><<<dim3(8, 8, BATCH), blk, 0, stream>>>(
      proj, src, sim, DS, DS, LS, S1, S1, S1);

  // 3. edit_weights = masked row softmax(sim) -> proj buffer (proj now dead)
  row_softmax_kernel<<<dim3(BATCH * LE), blk, 0, stream>>>(sim, smask, proj);

  // 4. src_weights = masked col softmax(sim), in-place
  col_softmax_kernel<<<dim3(LS / 64, BATCH), blk, 0, stream>>>(sim, emask);

  // 5. edit_ctx[b] = edit_weights[b] @ src[b]  (M=LE, N=DS, K=LS); B is K x N
  gemm_kernel<0, 1><<<dim3(8, 8, BATCH), blk, 0, stream>>>(
      proj, src, out_edit, LS, DS, DS, S1, S1, S1);

  // 6. src_ctx[b] = src_weights[b]^T @ edit[b]  (M=LS, N=DE, K=LE); A is K x M
  gemm_kernel<1, 1><<<dim3(8, 8, BATCH), blk, 0, stream>>>(
      sim, edit, out_src, LS, DE, DE, S1, S1, S1);
}

// Round 2
// 870.372 us; speedup vs baseline: 2.5152x; 2.5152x over previous
//
#include <hip/hip_runtime.h>
#include <math.h>

#define BATCH 16

typedef __attribute__((ext_vector_type(8))) short s16x8;
typedef __attribute__((ext_vector_type(8))) unsigned short u16x8;
typedef __attribute__((ext_vector_type(4))) float f32x4;

__device__ inline unsigned short f2bf_rn(float f) {
  unsigned u = __float_as_uint(f);
  u += 0x7FFF + ((u >> 16) & 1);
  return (unsigned short)(u >> 16);
}
__device__ inline float bf2f(unsigned short h) {
  return __uint_as_float(((unsigned)h) << 16);
}

#define LDK 40  // LDS row stride in bf16 elems for BK=32 (+8 pad -> 2-way max)

// ---------------------------------------------------------------------------
// Split-bf16 ("bf16x2") fp32-accurate GEMM: C = A * B^T, fp32 in/out.
// A: M x 1024 rm, B: N x 1024 rm, C: M x 1024 rm (all ld = 1024, K = 1024).
// 128x128 tile, 256 threads (4 waves, 2x2 of 64x64), BK=32,
// 3 MFMAs per fragment pair: al*bh + ah*bl + ah*bh  (lo*lo dropped).
// ---------------------------------------------------------------------------
__global__ __launch_bounds__(256) void gemm_split3(
    const float* __restrict__ A, const float* __restrict__ B,
    float* __restrict__ C, long long sA, long long sB, long long sC) {
  __shared__ unsigned short Ah[128 * LDK], Al[128 * LDK];
  __shared__ unsigned short Bh[128 * LDK], Bl[128 * LDK];
  const int z = blockIdx.z;
  A += (long long)z * sA; B += (long long)z * sB; C += (long long)z * sC;
  const int tid = threadIdx.x;
  const int bm = blockIdx.x << 7, bn = blockIdx.y << 7;
  const int wave = tid >> 6, lane = tid & 63;
  const int wm = (wave & 1) << 6, wn = (wave >> 1) << 6;
  const int fr = lane & 15, fk = (lane >> 4) << 3;

  f32x4 acc[4][4];
#pragma unroll
  for (int i = 0; i < 4; i++)
#pragma unroll
    for (int j = 0; j < 4; j++) acc[i][j] = (f32x4)(0.f);

  const int sr = tid >> 1;
  const int sk = (tid & 1) << 4;
  const float* pA = A + (size_t)(bm + sr) * 1024 + sk;
  const float* pB = B + (size_t)(bn + sr) * 1024 + sk;
  unsigned short* sAh = &Ah[sr * LDK + sk];
  unsigned short* sAl = &Al[sr * LDK + sk];
  unsigned short* sBh = &Bh[sr * LDK + sk];
  unsigned short* sBl = &Bl[sr * LDK + sk];

#pragma unroll 1
  for (int k0 = 0; k0 < 1024; k0 += 32) {
    f32x4 av[4], bv[4];
#pragma unroll
    for (int q = 0; q < 4; q++) av[q] = *(const f32x4*)(pA + k0 + (q << 2));
#pragma unroll
    for (int q = 0; q < 4; q++) bv[q] = *(const f32x4*)(pB + k0 + (q << 2));
    __syncthreads();
#pragma unroll
    for (int g = 0; g < 2; g++) {
      u16x8 h, l;
#pragma unroll
      for (int i = 0; i < 8; i++) {
        float f = av[(g << 1) + (i >> 2)][i & 3];
        unsigned short hh = f2bf_rn(f);
        h[i] = hh;
        l[i] = f2bf_rn(f - bf2f(hh));
      }
      *(u16x8*)(sAh + (g << 3)) = h;
      *(u16x8*)(sAl + (g << 3)) = l;
    }
#pragma unroll
    for (int g = 0; g < 2; g++) {
      u16x8 h, l;
#pragma unroll
      for (int i = 0; i < 8; i++) {
        float f = bv[(g << 1) + (i >> 2)][i & 3];
        unsigned short hh = f2bf_rn(f);
        h[i] = hh;
        l[i] = f2bf_rn(f - bf2f(hh));
      }
      *(u16x8*)(sBh + (g << 3)) = h;
      *(u16x8*)(sBl + (g << 3)) = l;
    }
    __syncthreads();

    s16x8 ah[4], al[4];
#pragma unroll
    for (int i = 0; i < 4; i++) {
      const int ro = (wm + (i << 4) + fr) * LDK + fk;
      ah[i] = *(const s16x8*)&Ah[ro];
      al[i] = *(const s16x8*)&Al[ro];
    }
#pragma unroll
    for (int j = 0; j < 4; j++) {
      const int ro = (wn + (j << 4) + fr) * LDK + fk;
      s16x8 bh = *(const s16x8*)&Bh[ro];
      s16x8 bl = *(const s16x8*)&Bl[ro];
#pragma unroll
      for (int i = 0; i < 4; i++) {
        acc[i][j] = __builtin_amdgcn_mfma_f32_16x16x32_bf16(al[i], bh, acc[i][j], 0, 0, 0);
        acc[i][j] = __builtin_amdgcn_mfma_f32_16x16x32_bf16(ah[i], bl, acc[i][j], 0, 0, 0);
        acc[i][j] = __builtin_amdgcn_mfma_f32_16x16x32_bf16(ah[i], bh, acc[i][j], 0, 0, 0);
      }
    }
  }
  const int cr = (lane >> 4) << 2;
#pragma unroll
  for (int i = 0; i < 4; i++)
#pragma unroll
    for (int r = 0; r < 4; r++) {
      float* cp = C + (size_t)(bm + wm + (i << 4) + cr + r) * 1024 + bn + wn + fr;
#pragma unroll
      for (int j = 0; j < 4; j++) cp[j << 4] = acc[i][j][r];
    }
}

// ---------------------------------------------------------------------------
// Plain bf16 GEMM: C = A * B^T fp32 out; A,B already bf16 (M/N x 1024 rm).
// ---------------------------------------------------------------------------
__global__ __launch_bounds__(256) void gemm_bf16(
    const unsigned short* __restrict__ A, const unsigned short* __restrict__ B,
    float* __restrict__ C, long long sA, long long sB, long long sC) {
  __shared__ unsigned short Ah[128 * LDK];
  __shared__ unsigned short Bh[128 * LDK];
  const int z = blockIdx.z;
  A += (long long)z * sA; B += (long long)z * sB; C += (long long)z * sC;
  const int tid = threadIdx.x;
  const int bm = blockIdx.x << 7, bn = blockIdx.y << 7;
  const int wave = tid >> 6, lane = tid & 63;
  const int wm = (wave & 1) << 6, wn = (wave >> 1) << 6;
  const int fr = lane & 15, fk = (lane >> 4) << 3;

  f32x4 acc[4][4];
#pragma unroll
  for (int i = 0; i < 4; i++)
#pragma unroll
    for (int j = 0; j < 4; j++) acc[i][j] = (f32x4)(0.f);

  const int sr = tid >> 1;
  const int sk = (tid & 1) << 4;
  const unsigned short* pA = A + (size_t)(bm + sr) * 1024 + sk;
  const unsigned short* pB = B + (size_t)(bn + sr) * 1024 + sk;
  unsigned short* sAh = &Ah[sr * LDK + sk];
  unsigned short* sBh = &Bh[sr * LDK + sk];

#pragma unroll 1
  for (int k0 = 0; k0 < 1024; k0 += 32) {
    f32x4 a0 = *(const f32x4*)(pA + k0);
    f32x4 a1 = *(const f32x4*)(pA + k0 + 8);
    f32x4 b0 = *(const f32x4*)(pB + k0);
    f32x4 b1 = *(const f32x4*)(pB + k0 + 8);
    __syncthreads();
    *(f32x4*)(sAh) = a0;
    *(f32x4*)(sAh + 8) = a1;
    *(f32x4*)(sBh) = b0;
    *(f32x4*)(sBh + 8) = b1;
    __syncthreads();

    s16x8 ah[4];
#pragma unroll
    for (int i = 0; i < 4; i++)
      ah[i] = *(const s16x8*)&Ah[(wm + (i << 4) + fr) * LDK + fk];
#pragma unroll
    for (int j = 0; j < 4; j++) {
      s16x8 bh = *(const s16x8*)&Bh[(wn + (j << 4) + fr) * LDK + fk];
#pragma unroll
      for (int i = 0; i < 4; i++)
        acc[i][j] = __builtin_amdgcn_mfma_f32_16x16x32_bf16(ah[i], bh, acc[i][j], 0, 0, 0);
    }
  }
  const int cr = (lane >> 4) << 2;
#pragma unroll
  for (int i = 0; i < 4; i++)
#pragma unroll
    for (int r = 0; r < 4; r++) {
      float* cp = C + (size_t)(bm + wm + (i << 4) + cr + r) * 1024 + bn + wn + fr;
#pragma unroll
      for (int j = 0; j < 4; j++) cp[j << 4] = acc[i][j][r];
    }
}

// ---------------------------------------------------------------------------
// Wave reductions
// ---------------------------------------------------------------------------
__device__ inline float waveMax(float v) {
#pragma unroll
  for (int o = 32; o > 0; o >>= 1) v = fmaxf(v, __shfl_down(v, o, 64));
  return v;
}
__device__ inline float waveSum(float v) {
#pragma unroll
  for (int o = 32; o > 0; o >>= 1) v += __shfl_down(v, o, 64);
  return v;
}

// ---------------------------------------------------------------------------
// edit_weights = masked row softmax(sim) -> bf16. One block per (b,e) row.
// ---------------------------------------------------------------------------
__global__ __launch_bounds__(256) void row_softmax_kernel(
    const float* __restrict__ sim, const int* __restrict__ smask,
    unsigned short* __restrict__ out) {
  const int row = blockIdx.x;  // b*1024 + e
  const int b = row >> 10;
  const float* x = sim + ((size_t)row << 10);
  const int* mk = smask + (b << 10);
  const int t = threadIdx.x;

  float4 v = ((const float4*)x)[t];
  int4 m = ((const int4*)mk)[t];
  float vv[4] = {v.x, v.y, v.z, v.w};
  const int mmv[4] = {m.x, m.y, m.z, m.w};

  float mx = -3.0e38f;
#pragma unroll
  for (int i = 0; i < 4; i++)
    if (!mmv[i]) mx = fmaxf(mx, vv[i]);

  __shared__ float red[4];
  float wmx = waveMax(mx);
  const int wave = t >> 6;
  if ((t & 63) == 0) red[wave] = wmx;
  __syncthreads();
  mx = fmaxf(fmaxf(red[0], red[1]), fmaxf(red[2], red[3]));
  __syncthreads();

  float s = 0.f;
#pragma unroll
  for (int i = 0; i < 4; i++) {
    float e = mmv[i] ? 0.f : __expf(vv[i] - mx);
    vv[i] = e;
    s += e;
  }
  float ws = waveSum(s);
  if ((t & 63) == 0) red[wave] = ws;
  __syncthreads();
  s = red[0] + red[1] + red[2] + red[3];
  float inv = 1.0f / s;

  ushort4 o;
  o.x = f2bf_rn(vv[0] * inv);
  o.y = f2bf_rn(vv[1] * inv);
  o.z = f2bf_rn(vv[2] * inv);
  o.w = f2bf_rn(vv[3] * inv);
  *(ushort4*)&out[((size_t)row << 10) + (t << 2)] = o;
}

// ---------------------------------------------------------------------------
// src_weights = masked col softmax(sim) over edit axis, written TRANSPOSED
// as bf16: wT[b][l][e]. Block = 64 cols (l) x 4 e-groups.
// ---------------------------------------------------------------------------
__global__ __launch_bounds__(256) void col_softmax_T(
    const float* __restrict__ sim, const int* __restrict__ emask,
    unsigned short* __restrict__ wT) {
  const int b = blockIdx.y;
  const int lane = threadIdx.x & 63;
  const int grp = threadIdx.x >> 6;
  const int l0 = blockIdx.x << 6;
  const float* base = sim + ((size_t)b << 20) + l0 + lane;
  const int* mk = emask + (b << 10);

  float mx = -3.0e38f, sum = 0.f;
  for (int e = grp; e < 1024; e += 4) {
    if (mk[e]) continue;
    float v = base[(size_t)e << 10];
    float nm = fmaxf(mx, v);
    sum = sum * __expf(mx - nm) + __expf(v - nm);
    mx = nm;
  }
  __shared__ float smx[4][64], ssum[4][64];
  smx[grp][lane] = mx;
  ssum[grp][lane] = sum;
  __syncthreads();
  float M = fmaxf(fmaxf(smx[0][lane], smx[1][lane]),
                  fmaxf(smx[2][lane], smx[3][lane]));
  float S = 0.f;
#pragma unroll
  for (int g = 0; g < 4; g++) S += ssum[g][lane] * __expf(smx[g][lane] - M);
  float inv = 1.0f / S;

  __shared__ unsigned short tile[64][72];
  const int r = threadIdx.x >> 2, seg = (threadIdx.x & 3) << 4;
  for (int c = 0; c < 1024; c += 64) {
#pragma unroll
    for (int i = 0; i < 16; i++) {
      int e = c + (grp << 4) + i;
      float w = mk[e] ? 0.f : __expf(base[(size_t)e << 10] - M) * inv;
      tile[lane][(grp << 4) + i] = f2bf_rn(w);
    }
    __syncthreads();
    f32x4 v0 = *(const f32x4*)&tile[r][seg];
    f32x4 v1 = *(const f32x4*)&tile[r][seg + 8];
    size_t o = ((size_t)((b << 10) + l0 + r) << 10) + c + seg;
    *(f32x4*)&wT[o] = v0;
    *(f32x4*)&wT[o + 8] = v1;
    __syncthreads();
  }
}

// ---------------------------------------------------------------------------
// Transpose + fp32->bf16: XT[b][d][l] = X[b][l][d]. 64x64 tiles.
// ---------------------------------------------------------------------------
__global__ __launch_bounds__(256) void transpose_cvt(
    const float* __restrict__ X, unsigned short* __restrict__ XT) {
  __shared__ unsigned short ts[64][72];
  const int b = blockIdx.z;
  const int d0 = blockIdx.x << 6, l0 = blockIdx.y << 6;
  const int t = threadIdx.x;
  const float* Xb = X + ((size_t)b << 20);
  unsigned short* Tb = XT + ((size_t)b << 20);
#pragma unroll
  for (int p = 0; p < 4; p++) {
    int row = (p << 4) + (t >> 4);
    int col = (t & 15) << 2;
    f32x4 v = *(const f32x4*)&Xb[((size_t)(l0 + row) << 10) + d0 + col];
#pragma unroll
    for (int i = 0; i < 4; i++) ts[col + i][row] = f2bf_rn(v[i]);
  }
  __syncthreads();
  const int dr = t >> 2, seg = (t & 3) << 4;
  f32x4 v0 = *(const f32x4*)&ts[dr][seg];
  f32x4 v1 = *(const f32x4*)&ts[dr][seg + 8];
  size_t o = ((size_t)(d0 + dr) << 10) + l0 + seg;
  *(f32x4*)&Tb[o] = v0;
  *(f32x4*)&Tb[o + 8] = v1;
}

// ---------------------------------------------------------------------------
// proj(split3) -> sim(split3) -> row softmax(bf16 w) -> col softmax(bf16 wT)
// -> transpose src/edit to bf16 -> two plain-bf16 ctx GEMMs.
// ws map (128MB): [0,64MB) proj fp32, later wE bf16 @0 + wT bf16 @32MB;
//                 [64,128MB) sim fp32, later srcT bf16 @64MB + editT @96MB.
// ---------------------------------------------------------------------------
extern "C" void kernel_launch(void* const* d_in, const int* in_sizes, int n_in,
                              void* d_out, int out_size, void* d_ws,
                              size_t ws_size, hipStream_t stream) {
  const float* edit = (const float*)d_in[0];
  const float* src = (const float*)d_in[1];
  const int* emask = (const int*)d_in[2];
  const int* smask = (const int*)d_in[3];
  const float* W = (const float*)d_in[4];

  float* out_edit = (float*)d_out;
  float* out_src = (float*)d_out + ((size_t)BATCH << 20);

  char* ws = (char*)d_ws;
  float* proj = (float*)ws;
  float* sim = (float*)(ws + ((size_t)64 << 20));
  unsigned short* wE = (unsigned short*)ws;
  unsigned short* wST = (unsigned short*)(ws + ((size_t)32 << 20));
  unsigned short* srcT = (unsigned short*)(ws + ((size_t)64 << 20));
  unsigned short* editT = (unsigned short*)(ws + ((size_t)96 << 20));

  const long long S1 = 1LL << 20;
  dim3 blk(256);

  // 1. proj = edit @ W^T   (M = 16*1024 flattened, N = 1024)
  gemm_split3<<<dim3(128, 8, 1), blk, 0, stream>>>(edit, W, proj, 0, 0, 0);
  // 2. sim[b] = proj[b] @ src[b]^T
  gemm_split3<<<dim3(8, 8, BATCH), blk, 0, stream>>>(proj, src, sim, S1, S1, S1);
  // 3. edit_weights (bf16) -> wE
  row_softmax_kernel<<<dim3(BATCH << 10), blk, 0, stream>>>(sim, smask, wE);
  // 4. src_weights transposed (bf16) -> wST
  col_softmax_T<<<dim3(16, BATCH), blk, 0, stream>>>(sim, emask, wST);
  // 5. srcT, editT (bf16)
  transpose_cvt<<<dim3(16, 16, BATCH), blk, 0, stream>>>(src, srcT);
  transpose_cvt<<<dim3(16, 16, BATCH), blk, 0, stream>>>(edit, editT);
  // 6. edit_ctx[b] = wE[b] @ srcT[b]^T
  gemm_bf16<<<dim3(8, 8, BATCH), blk, 0, stream>>>(wE, srcT, out_edit, S1, S1, S1);
  // 7. src_ctx[b] = wST[b] @ editT[b]^T
  gemm_bf16<<<dim3(8, 8, BATCH), blk, 0, stream>>>(wST, editT, out_src, S1, S1, S1);
}

// Round 3
// 683.533 us; speedup vs baseline: 3.2028x; 1.2733x over previous
//
#include <hip/hip_runtime.h>
#include <math.h>

#define BATCH 16

typedef __attribute__((ext_vector_type(8))) short s16x8;
typedef __attribute__((ext_vector_type(8))) unsigned short u16x8;
typedef __attribute__((ext_vector_type(4))) float f32x4;

__device__ inline unsigned short f2bf_rn(float f) {
  unsigned u = __float_as_uint(f);
  u += 0x7FFF + ((u >> 16) & 1);
  return (unsigned short)(u >> 16);
}
__device__ inline float bf2f(unsigned short h) {
  return __uint_as_float(((unsigned)h) << 16);
}

#define LDK 40  // LDS row stride (bf16) for BK=32: pad +8 -> conflict-free frag reads

// ---------------------------------------------------------------------------
// Elementwise fp32 -> (bf16 hi, bf16 lo) split. 4 elems/thread.
// ---------------------------------------------------------------------------
__global__ __launch_bounds__(256) void cvt_split(
    const float* __restrict__ X, unsigned short* __restrict__ H,
    unsigned short* __restrict__ L) {
  const size_t i = (((size_t)blockIdx.x << 8) + threadIdx.x) << 2;
  f32x4 v = *(const f32x4*)(X + i);
  ushort4 h, l;
  h.x = f2bf_rn(v[0]); l.x = f2bf_rn(v[0] - bf2f(h.x));
  h.y = f2bf_rn(v[1]); l.y = f2bf_rn(v[1] - bf2f(h.y));
  h.z = f2bf_rn(v[2]); l.z = f2bf_rn(v[2] - bf2f(h.z));
  h.w = f2bf_rn(v[3]); l.w = f2bf_rn(v[3] - bf2f(h.w));
  *(ushort4*)(H + i) = h;
  *(ushort4*)(L + i) = l;
}

// ---------------------------------------------------------------------------
// Split-bf16 GEMM, hi/lo preconverted: C = A*B^T fp32-accurate.
// A: (AH,AL) M x 1024 rm bf16; B: (BH,BL) N x 1024 rm bf16.
// 3 MFMAs per fragment pair: al*bh + ah*bl + ah*bh.
// SPLIT_OUT=1: write C as (CH,CL) bf16 hi/lo. SPLIT_OUT=0: fp32 C.
// ---------------------------------------------------------------------------
template <int SPLIT_OUT>
__global__ __launch_bounds__(256) void gemm_split3b(
    const unsigned short* __restrict__ AH, const unsigned short* __restrict__ AL,
    const unsigned short* __restrict__ BH, const unsigned short* __restrict__ BL,
    void* __restrict__ Cout, void* __restrict__ CoutL,
    long long sA, long long sB, long long sC) {
  __shared__ unsigned short Ahs[128 * LDK], Als[128 * LDK];
  __shared__ unsigned short Bhs[128 * LDK], Bls[128 * LDK];
  const int z = blockIdx.z;
  const size_t oA = (size_t)z * sA, oB = (size_t)z * sB;
  const int tid = threadIdx.x;
  const int bm = blockIdx.x << 7, bn = blockIdx.y << 7;
  const int wave = tid >> 6, lane = tid & 63;
  const int wm = (wave & 1) << 6, wn = (wave >> 1) << 6;
  const int fr = lane & 15, fk = (lane >> 4) << 3;

  f32x4 acc[4][4];
#pragma unroll
  for (int i = 0; i < 4; i++)
#pragma unroll
    for (int j = 0; j < 4; j++) acc[i][j] = (f32x4)(0.f);

  const int sr = tid >> 1, sk = (tid & 1) << 4;
  const unsigned short* pAH = AH + oA + (size_t)(bm + sr) * 1024 + sk;
  const unsigned short* pAL = AL + oA + (size_t)(bm + sr) * 1024 + sk;
  const unsigned short* pBH = BH + oB + (size_t)(bn + sr) * 1024 + sk;
  const unsigned short* pBL = BL + oB + (size_t)(bn + sr) * 1024 + sk;
  unsigned short* wAh = &Ahs[sr * LDK + sk];
  unsigned short* wAl = &Als[sr * LDK + sk];
  unsigned short* wBh = &Bhs[sr * LDK + sk];
  unsigned short* wBl = &Bls[sr * LDK + sk];

#pragma unroll 1
  for (int k0 = 0; k0 < 1024; k0 += 32) {
    u16x8 ah0 = *(const u16x8*)(pAH + k0), ah1 = *(const u16x8*)(pAH + k0 + 8);
    u16x8 al0 = *(const u16x8*)(pAL + k0), al1 = *(const u16x8*)(pAL + k0 + 8);
    u16x8 bh0 = *(const u16x8*)(pBH + k0), bh1 = *(const u16x8*)(pBH + k0 + 8);
    u16x8 bl0 = *(const u16x8*)(pBL + k0), bl1 = *(const u16x8*)(pBL + k0 + 8);
    __syncthreads();
    *(u16x8*)(wAh) = ah0; *(u16x8*)(wAh + 8) = ah1;
    *(u16x8*)(wAl) = al0; *(u16x8*)(wAl + 8) = al1;
    *(u16x8*)(wBh) = bh0; *(u16x8*)(wBh + 8) = bh1;
    *(u16x8*)(wBl) = bl0; *(u16x8*)(wBl + 8) = bl1;
    __syncthreads();

    s16x8 ah[4], al[4];
#pragma unroll
    for (int i = 0; i < 4; i++) {
      const int ro = (wm + (i << 4) + fr) * LDK + fk;
      ah[i] = *(const s16x8*)&Ahs[ro];
      al[i] = *(const s16x8*)&Als[ro];
    }
#pragma unroll
    for (int j = 0; j < 4; j++) {
      const int ro = (wn + (j << 4) + fr) * LDK + fk;
      s16x8 bh = *(const s16x8*)&Bhs[ro];
      s16x8 bl = *(const s16x8*)&Bls[ro];
#pragma unroll
      for (int i = 0; i < 4; i++) {
        acc[i][j] = __builtin_amdgcn_mfma_f32_16x16x32_bf16(al[i], bh, acc[i][j], 0, 0, 0);
        acc[i][j] = __builtin_amdgcn_mfma_f32_16x16x32_bf16(ah[i], bl, acc[i][j], 0, 0, 0);
        acc[i][j] = __builtin_amdgcn_mfma_f32_16x16x32_bf16(ah[i], bh, acc[i][j], 0, 0, 0);
      }
    }
  }
  const int cr = (lane >> 4) << 2;
  if (SPLIT_OUT) {
    unsigned short* CH = (unsigned short*)Cout + (size_t)z * sC;
    unsigned short* CL = (unsigned short*)CoutL + (size_t)z * sC;
#pragma unroll
    for (int i = 0; i < 4; i++)
#pragma unroll
      for (int r = 0; r < 4; r++) {
        size_t base = (size_t)(bm + wm + (i << 4) + cr + r) * 1024 + bn + wn + fr;
#pragma unroll
        for (int j = 0; j < 4; j++) {
          float f = acc[i][j][r];
          unsigned short h = f2bf_rn(f);
          CH[base + (j << 4)] = h;
          CL[base + (j << 4)] = f2bf_rn(f - bf2f(h));
        }
      }
  } else {
    float* C = (float*)Cout + (size_t)z * sC;
#pragma unroll
    for (int i = 0; i < 4; i++)
#pragma unroll
      for (int r = 0; r < 4; r++) {
        float* cp = C + (size_t)(bm + wm + (i << 4) + cr + r) * 1024 + bn + wn + fr;
#pragma unroll
        for (int j = 0; j < 4; j++) cp[j << 4] = acc[i][j][r];
      }
  }
}

// ---------------------------------------------------------------------------
// Plain bf16 GEMM: C = A * B^T fp32 out; A,B bf16 (M/N x 1024 rm).
// ---------------------------------------------------------------------------
__global__ __launch_bounds__(256) void gemm_bf16(
    const unsigned short* __restrict__ A, const unsigned short* __restrict__ B,
    float* __restrict__ C, long long sA, long long sB, long long sC) {
  __shared__ unsigned short Ah[128 * LDK];
  __shared__ unsigned short Bh[128 * LDK];
  const int z = blockIdx.z;
  A += (size_t)z * sA; B += (size_t)z * sB; C += (size_t)z * sC;
  const int tid = threadIdx.x;
  const int bm = blockIdx.x << 7, bn = blockIdx.y << 7;
  const int wave = tid >> 6, lane = tid & 63;
  const int wm = (wave & 1) << 6, wn = (wave >> 1) << 6;
  const int fr = lane & 15, fk = (lane >> 4) << 3;

  f32x4 acc[4][4];
#pragma unroll
  for (int i = 0; i < 4; i++)
#pragma unroll
    for (int j = 0; j < 4; j++) acc[i][j] = (f32x4)(0.f);

  const int sr = tid >> 1, sk = (tid & 1) << 4;
  const unsigned short* pA = A + (size_t)(bm + sr) * 1024 + sk;
  const unsigned short* pB = B + (size_t)(bn + sr) * 1024 + sk;
  unsigned short* sAh = &Ah[sr * LDK + sk];
  unsigned short* sBh = &Bh[sr * LDK + sk];

#pragma unroll 1
  for (int k0 = 0; k0 < 1024; k0 += 32) {
    u16x8 a0 = *(const u16x8*)(pA + k0), a1 = *(const u16x8*)(pA + k0 + 8);
    u16x8 b0 = *(const u16x8*)(pB + k0), b1 = *(const u16x8*)(pB + k0 + 8);
    __syncthreads();
    *(u16x8*)(sAh) = a0; *(u16x8*)(sAh + 8) = a1;
    *(u16x8*)(sBh) = b0; *(u16x8*)(sBh + 8) = b1;
    __syncthreads();

    s16x8 ah[4];
#pragma unroll
    for (int i = 0; i < 4; i++)
      ah[i] = *(const s16x8*)&Ah[(wm + (i << 4) + fr) * LDK + fk];
#pragma unroll
    for (int j = 0; j < 4; j++) {
      s16x8 bh = *(const s16x8*)&Bh[(wn + (j << 4) + fr) * LDK + fk];
#pragma unroll
      for (int i = 0; i < 4; i++)
        acc[i][j] = __builtin_amdgcn_mfma_f32_16x16x32_bf16(ah[i], bh, acc[i][j], 0, 0, 0);
    }
  }
  const int cr = (lane >> 4) << 2;
#pragma unroll
  for (int i = 0; i < 4; i++)
#pragma unroll
    for (int r = 0; r < 4; r++) {
      float* cp = C + (size_t)(bm + wm + (i << 4) + cr + r) * 1024 + bn + wn + fr;
#pragma unroll
      for (int j = 0; j < 4; j++) cp[j << 4] = acc[i][j][r];
    }
}

// ---------------------------------------------------------------------------
// Wave reductions
// ---------------------------------------------------------------------------
__device__ inline float waveMax(float v) {
#pragma unroll
  for (int o = 32; o > 0; o >>= 1) v = fmaxf(v, __shfl_down(v, o, 64));
  return v;
}
__device__ inline float waveSum(float v) {
#pragma unroll
  for (int o = 32; o > 0; o >>= 1) v += __shfl_down(v, o, 64);
  return v;
}

// ---------------------------------------------------------------------------
// edit_weights = masked row softmax(sim) -> bf16. One block per (b,e) row.
// ---------------------------------------------------------------------------
__global__ __launch_bounds__(256) void row_softmax_kernel(
    const float* __restrict__ sim, const int* __restrict__ smask,
    unsigned short* __restrict__ out) {
  const int row = blockIdx.x;  // b*1024 + e
  const int b = row >> 10;
  const float* x = sim + ((size_t)row << 10);
  const int* mk = smask + (b << 10);
  const int t = threadIdx.x;

  float4 v = ((const float4*)x)[t];
  int4 m = ((const int4*)mk)[t];
  float vv[4] = {v.x, v.y, v.z, v.w};
  const int mmv[4] = {m.x, m.y, m.z, m.w};

  float mx = -3.0e38f;
#pragma unroll
  for (int i = 0; i < 4; i++)
    if (!mmv[i]) mx = fmaxf(mx, vv[i]);

  __shared__ float red[4];
  float wmx = waveMax(mx);
  const int wave = t >> 6;
  if ((t & 63) == 0) red[wave] = wmx;
  __syncthreads();
  mx = fmaxf(fmaxf(red[0], red[1]), fmaxf(red[2], red[3]));
  __syncthreads();

  float s = 0.f;
#pragma unroll
  for (int i = 0; i < 4; i++) {
    float e = mmv[i] ? 0.f : __expf(vv[i] - mx);
    vv[i] = e;
    s += e;
  }
  float ws = waveSum(s);
  if ((t & 63) == 0) red[wave] = ws;
  __syncthreads();
  s = red[0] + red[1] + red[2] + red[3];
  float inv = 1.0f / s;

  ushort4 o;
  o.x = f2bf_rn(vv[0] * inv);
  o.y = f2bf_rn(vv[1] * inv);
  o.z = f2bf_rn(vv[2] * inv);
  o.w = f2bf_rn(vv[3] * inv);
  *(ushort4*)&out[((size_t)row << 10) + (t << 2)] = o;
}

// ---------------------------------------------------------------------------
// Col-softmax phase A: partial (max, sum) over 64-row e-chunks.
// grid (4 l-blocks of 256, 16 e-chunks, B). Coalesced 1KB reads.
// ---------------------------------------------------------------------------
__global__ __launch_bounds__(256) void col_partial(
    const float* __restrict__ sim, const int* __restrict__ emask,
    float* __restrict__ pmax, float* __restrict__ psum) {
  const int b = blockIdx.z;
  const int ec = blockIdx.y;
  const int l = (blockIdx.x << 8) + threadIdx.x;
  const float* p = sim + ((size_t)b << 20) + (((size_t)ec << 6) << 10) + l;
  const int* mk = emask + (b << 10) + (ec << 6);
  float mx0 = -1.0e30f, s0 = 0.f, mx1 = -1.0e30f, s1 = 0.f;
#pragma unroll 4
  for (int i = 0; i < 64; i += 2) {
    float v0 = mk[i] ? -3.0e38f : p[(size_t)i << 10];
    float v1 = mk[i + 1] ? -3.0e38f : p[(size_t)(i + 1) << 10];
    float n0 = fmaxf(mx0, v0);
    s0 = s0 * __expf(mx0 - n0) + __expf(v0 - n0);
    mx0 = n0;
    float n1 = fmaxf(mx1, v1);
    s1 = s1 * __expf(mx1 - n1) + __expf(v1 - n1);
    mx1 = n1;
  }
  float M = fmaxf(mx0, mx1);
  float S = s0 * __expf(mx0 - M) + s1 * __expf(mx1 - M);
  const int o = (((b << 4) + ec) << 10) + l;
  pmax[o] = M;
  psum[o] = S;
}

// ---------------------------------------------------------------------------
// Col-softmax phase C: combine partials -> per-column (M, 1/S); compute
// weights for a 64l x 64e tile; write TRANSPOSED bf16 wT[b][l][e].
// grid (16 l-tiles, 16 e-tiles, B).
// ---------------------------------------------------------------------------
__global__ __launch_bounds__(256) void col_weights_T(
    const float* __restrict__ sim, const int* __restrict__ emask,
    const float* __restrict__ pmax, const float* __restrict__ psum,
    unsigned short* __restrict__ wT) {
  const int b = blockIdx.z;
  const int l0 = blockIdx.x << 6;
  const int e0 = blockIdx.y << 6;
  const int t = threadIdx.x;
  __shared__ float Ml[64], Il[64];
  __shared__ int msk[64];
  __shared__ float gm[4][64], gs[4][64];
  __shared__ unsigned short tile[64][72];

  {
    const int ll = t & 63, g = t >> 6;
    float m = -1.0e30f, s = 0.f;
#pragma unroll
    for (int q = 0; q < 4; q++) {
      int ec = g + (q << 2);
      const int o = (((b << 4) + ec) << 10) + l0 + ll;
      float pm = pmax[o], ps = psum[o];
      float nm = fmaxf(m, pm);
      s = s * __expf(m - nm) + ps * __expf(pm - nm);
      m = nm;
    }
    gm[g][ll] = m;
    gs[g][ll] = s;
    __syncthreads();
    if (t < 64) {
      float M = fmaxf(fmaxf(gm[0][t], gm[1][t]), fmaxf(gm[2][t], gm[3][t]));
      float S = 0.f;
#pragma unroll
      for (int q = 0; q < 4; q++) S += gs[q][t] * __expf(gm[q][t] - M);
      Ml[t] = M;
      Il[t] = 1.0f / S;
      msk[t] = emask[(b << 10) + e0 + t];
    }
    __syncthreads();
  }

  const int lane = t & 63, wv = t >> 6;
#pragma unroll
  for (int i = 0; i < 16; i++) {
    const int el = (wv << 4) + i;
    float v = sim[((size_t)b << 20) + ((size_t)(e0 + el) << 10) + l0 + lane];
    float w = msk[el] ? 0.f : __expf(v - Ml[lane]) * Il[lane];
    tile[lane][el] = f2bf_rn(w);
  }
  __syncthreads();
  const int r = t >> 2, seg = (t & 3) << 4;
  u16x8 v0 = *(const u16x8*)&tile[r][seg];
  u16x8 v1 = *(const u16x8*)&tile[r][seg + 8];
  size_t o = ((size_t)((b << 10) + l0 + r) << 10) + e0 + seg;
  *(u16x8*)&wT[o] = v0;
  *(u16x8*)&wT[o + 8] = v1;
}

// ---------------------------------------------------------------------------
// bf16 64x64 transpose: XT[b][d][l] = X[b][l][d].
// ---------------------------------------------------------------------------
__global__ __launch_bounds__(256) void transpose16(
    const unsigned short* __restrict__ X, unsigned short* __restrict__ XT) {
  __shared__ unsigned short ts[64][72];
  const int b = blockIdx.z;
  const int d0 = blockIdx.x << 6, l0 = blockIdx.y << 6;
  const int t = threadIdx.x;
  const unsigned short* Xb = X + ((size_t)b << 20);
  unsigned short* Tb = XT + ((size_t)b << 20);
  const int row = t >> 2, seg = (t & 3) << 4;
  u16x8 v0 = *(const u16x8*)&Xb[((size_t)(l0 + row) << 10) + d0 + seg];
  u16x8 v1 = *(const u16x8*)&Xb[((size_t)(l0 + row) << 10) + d0 + seg + 8];
#pragma unroll
  for (int i = 0; i < 8; i++) ts[seg + i][row] = v0[i];
#pragma unroll
  for (int i = 0; i < 8; i++) ts[seg + 8 + i][row] = v1[i];
  __syncthreads();
  u16x8 o0 = *(const u16x8*)&ts[row][seg];
  u16x8 o1 = *(const u16x8*)&ts[row][seg + 8];
  size_t o = ((size_t)(d0 + row) << 10) + l0 + seg;
  *(u16x8*)&Tb[o] = o0;
  *(u16x8*)&Tb[o + 8] = o1;
}

// ---------------------------------------------------------------------------
// Buffer plan (ws = 128 MB, d_out = 128 MB used as scratch until outputs):
//  ws[0,32):    editH                 (live到 src_ctx transposes)
//  ws[32,64):   srcH  -> editT        (after srcT transpose consumes srcH)
//  ws[64,96):   projH -> wE
//  ws[96,128):  projL -> wST
//  dout[0,32):  editL -> sim(lo half) -> out_edit
//  dout[32,64):          sim(hi half) -> out_edit
//  dout[64,96): srcL  -> pmax/psum(2MB) -> srcT -> out_src
//  dout[96,100): WH,WL                 -> out_src
// Order: cvt x3, projGEMM(split-out), simGEMM(fp32), row_softmax,
//        col_partial, col_weights_T, srcT, editT, edit_ctx, src_ctx.
// ---------------------------------------------------------------------------
extern "C" void kernel_launch(void* const* d_in, const int* in_sizes, int n_in,
                              void* d_out, int out_size, void* d_ws,
                              size_t ws_size, hipStream_t stream) {
  const float* edit = (const float*)d_in[0];
  const float* src = (const float*)d_in[1];
  const int* emask = (const int*)d_in[2];
  const int* smask = (const int*)d_in[3];
  const float* W = (const float*)d_in[4];

  char* ws = (char*)d_ws;
  char* dob = (char*)d_out;

  unsigned short* eH = (unsigned short*)ws;
  unsigned short* sH = (unsigned short*)(ws + ((size_t)32 << 20));
  unsigned short* pH = (unsigned short*)(ws + ((size_t)64 << 20));
  unsigned short* pL = (unsigned short*)(ws + ((size_t)96 << 20));
  unsigned short* wE = pH;   // after proj GEMM consumed
  unsigned short* wST = pL;
  unsigned short* editT = sH;  // after srcH consumed by its transpose

  unsigned short* eL = (unsigned short*)dob;
  unsigned short* sL = (unsigned short*)(dob + ((size_t)64 << 20));
  unsigned short* WH = (unsigned short*)(dob + ((size_t)96 << 20));
  unsigned short* WL = (unsigned short*)(dob + ((size_t)98 << 20));
  float* sim = (float*)dob;                                  // [0,64)
  float* pmax = (float*)(dob + ((size_t)64 << 20));
  float* psum = (float*)(dob + ((size_t)65 << 20));
  unsigned short* srcT = (unsigned short*)(dob + ((size_t)64 << 20));
  float* out_edit = (float*)dob;
  float* out_src = (float*)(dob + ((size_t)64 << 20));

  const long long S1 = 1LL << 20;
  dim3 blk(256);

  // P1: split conversions
  cvt_split<<<dim3(16384), blk, 0, stream>>>(edit, eH, eL);
  cvt_split<<<dim3(16384), blk, 0, stream>>>(src, sH, sL);
  cvt_split<<<dim3(1024), blk, 0, stream>>>(W, WH, WL);

  // P2: proj = edit @ W^T -> hi/lo bf16 (M=16384 flattened, N=1024)
  gemm_split3b<1><<<dim3(128, 8, 1), blk, 0, stream>>>(
      eH, eL, WH, WL, (void*)pH, (void*)pL, 0, 0, 0);

  // P3: sim[b] = proj[b] @ src[b]^T -> fp32 (in d_out[0,64MB))
  gemm_split3b<0><<<dim3(8, 8, BATCH), blk, 0, stream>>>(
      pH, pL, sH, sL, (void*)sim, nullptr, S1, S1, S1);

  // P4: softmaxes
  row_softmax_kernel<<<dim3(BATCH << 10), blk, 0, stream>>>(sim, smask, wE);
  col_partial<<<dim3(4, 16, BATCH), blk, 0, stream>>>(sim, emask, pmax, psum);
  col_weights_T<<<dim3(16, 16, BATCH), blk, 0, stream>>>(sim, emask, pmax, psum, wST);

  // P5: transposes (bf16): srcT = srcH^T, editT = editH^T (overwrites srcH)
  transpose16<<<dim3(16, 16, BATCH), blk, 0, stream>>>(sH, srcT);
  transpose16<<<dim3(16, 16, BATCH), blk, 0, stream>>>(eH, editT);

  // P6: ctx GEMMs. edit_ctx FIRST (reads srcT in dout[64,96) before src_ctx
  // overwrites it; writes dout[0,64) over dead sim).
  gemm_bf16<<<dim3(8, 8, BATCH), blk, 0, stream>>>(wE, srcT, out_edit, S1, S1, S1);
  gemm_bf16<<<dim3(8, 8, BATCH), blk, 0, stream>>>(wST, editT, out_src, S1, S1, S1);
}